// Round 1
// baseline (565.018 us; speedup 1.0000x reference)
//
#include <hip/hip_runtime.h>
#include <stdint.h>

#define NND 200000   // N nodes
// D_IN = D_OUT = 256, B = 256

typedef unsigned short u16;
typedef __attribute__((ext_vector_type(4))) float f4;
typedef __attribute__((ext_vector_type(4))) int   i4;
typedef __attribute__((ext_vector_type(8))) short s8;   // 8 bf16 (4 VGPRs) - MFMA A/B frag
typedef __attribute__((ext_vector_type(4))) short s4;
typedef __attribute__((ext_vector_type(4))) float acc4; // MFMA C/D frag

__device__ __forceinline__ short f2bf(float f) {
    union { float f; uint32_t u; } v; v.f = f;
    uint32_t r = v.u + 0x7FFFu + ((v.u >> 16) & 1u);   // RNE
    return (short)(r >> 16);
}

__device__ __forceinline__ void gld16(const void* g, const void* l) {
    __builtin_amdgcn_global_load_lds(
        (const __attribute__((address_space(1))) void*)g,
        (__attribute__((address_space(3))) void*)l, 16, 0, 0);
}

// ---------------- prep: W fp32 -> bf16 ----------------
__global__ __launch_bounds__(256) void k_prep(const float* __restrict__ Wt,
                                              const float* __restrict__ Wg,
                                              u16* __restrict__ wtb,
                                              u16* __restrict__ wgb) {
    int i = blockIdx.x * 256 + threadIdx.x;   // 256 blocks -> 65536 exactly
    wtb[i] = (u16)f2bf(Wt[i]);
    wgb[i] = (u16)f2bf(Wg[i]);
}

// ---------------- pass 1: h_t[d][n] = (nodes@Wt.T+bt) * sigmoid(nodes@Wg.T+bg), transposed ----------------
// grid (4, 1563): x = d-block (64 d), y = row tile (128 nodes). block 256 = 4 waves (2x2).
__global__ __launch_bounds__(256) void k_h(const float* __restrict__ nodes,
                                           const u16* __restrict__ wtb,
                                           const u16* __restrict__ wgb,
                                           const float* __restrict__ btp,
                                           const float* __restrict__ bgp,
                                           u16* __restrict__ h_t) {
    __shared__ __align__(16) float As[128 * 64];   // 32 KB, [row][k] swizzled 16B granules
    __shared__ __align__(16) u16 Bs[2][64 * 64];   // 2 x 8 KB, [d][k] bf16 swizzled

    const int tid  = threadIdx.x;
    const int lane = tid & 63, wave = tid >> 6;
    const int quad = lane >> 4, l16 = lane & 15;
    const int d0 = blockIdx.x * 64;
    const int n0 = blockIdx.y * 128;
    const int wm = wave & 1;     // row half (64)
    const int wd = wave >> 1;    // d half (32)

    acc4 at_[4][2], ag_[4][2];
#pragma unroll
    for (int rt = 0; rt < 4; ++rt)
#pragma unroll
        for (int dt = 0; dt < 2; ++dt) { at_[rt][dt] = (acc4)0.0f; ag_[rt][dt] = (acc4)0.0f; }

    for (int kt = 0; kt < 4; ++kt) {
        const int k0 = kt * 64;
        // stage A: 128x64 fp32; slot c in row holds data granule c^(row&15)
#pragma unroll
        for (int i = 0; i < 8; ++i) {
            int g = i * 256 + tid;
            int row = g >> 4, c = g & 15;
            int srow = n0 + row; srow = srow < NND ? srow : (NND - 1);  // clamp last tile
            gld16(nodes + (size_t)srow * 256 + k0 + ((c ^ (row & 15)) << 2), As + g * 4);
        }
        // stage Wt/Wg: 64x64 bf16 each; slot c holds granule c^(d&7)
#pragma unroll
        for (int i = 0; i < 2; ++i) {
            int g = i * 256 + tid;
            int dr = g >> 3, c = g & 7;
            size_t off = (size_t)(d0 + dr) * 256 + k0 + ((c ^ (dr & 7)) << 3);
            gld16(wtb + off, &Bs[0][g * 8]);
            gld16(wgb + off, &Bs[1][g * 8]);
        }
        __syncthreads();
#pragma unroll
        for (int ks = 0; ks < 2; ++ks) {
            s8 af[4];
#pragma unroll
            for (int rt = 0; rt < 4; ++rt) {
                int row = wm * 64 + rt * 16 + l16;
                int gi = ks * 8 + quad * 2;
                const float* base = As + row * 64;
                f4 a0 = *(const f4*)(base + ((gi ^ l16) << 2));
                f4 a1 = *(const f4*)(base + (((gi + 1) ^ l16) << 2));
                s8 t;
                t[0] = f2bf(a0.x); t[1] = f2bf(a0.y); t[2] = f2bf(a0.z); t[3] = f2bf(a0.w);
                t[4] = f2bf(a1.x); t[5] = f2bf(a1.y); t[6] = f2bf(a1.z); t[7] = f2bf(a1.w);
                af[rt] = t;
            }
#pragma unroll
            for (int dt = 0; dt < 2; ++dt) {
                int d = wd * 32 + dt * 16 + l16;
                int slot = (ks * 4 + quad) ^ (l16 & 7);
                s8 bT = *(const s8*)&Bs[0][d * 64 + slot * 8];
                s8 bG = *(const s8*)&Bs[1][d * 64 + slot * 8];
#pragma unroll
                for (int rt = 0; rt < 4; ++rt) {
                    at_[rt][dt] = __builtin_amdgcn_mfma_f32_16x16x32_bf16(af[rt], bT, at_[rt][dt], 0, 0, 0);
                    ag_[rt][dt] = __builtin_amdgcn_mfma_f32_16x16x32_bf16(af[rt], bG, ag_[rt][dt], 0, 0, 0);
                }
            }
        }
        __syncthreads();
    }

    // epilogue: h = (data+bt)*sigmoid(gate+bg); transpose via LDS; store h_t[d][n] coalesced
    u16* Hs = (u16*)As;  // [64 d][stride 136] -> 17408 B, fits in As
#pragma unroll
    for (int dt = 0; dt < 2; ++dt) {
        int dl = wd * 32 + dt * 16 + l16;
        float btv = btp[d0 + dl], bgv = bgp[d0 + dl];
#pragma unroll
        for (int rt = 0; rt < 4; ++rt) {
            s4 hv;
#pragma unroll
            for (int r = 0; r < 4; ++r) {
                float dat = at_[rt][dt][r] + btv;
                float gat = ag_[rt][dt][r] + bgv;
                float sg = 1.0f / (1.0f + __expf(-gat));
                hv[r] = f2bf(dat * sg);
            }
            *(s4*)&Hs[dl * 136 + wm * 64 + rt * 16 + quad * 4] = hv;
        }
    }
    __syncthreads();
#pragma unroll
    for (int i = 0; i < 4; ++i) {
        int g = i * 256 + tid;
        int dl = g >> 4, c = g & 15;
        int n = n0 + c * 8;
        if (n < NND) {
            f4 v = *(const f4*)&Hs[dl * 136 + c * 8];
            *(f4*)(h_t + (size_t)(d0 + dl) * NND + n) = v;
        }
    }
}

// ---------------- pass 2: res = mask @ h_t^T, split-K with fp32 atomics ----------------
// grid (4, 125): x = output 128x128 tile, y = K-split (1600 nodes each). block 256 = 4 waves (2x2).
__global__ __launch_bounds__(256) void k_res(const int* __restrict__ masks,
                                             const u16* __restrict__ h_t,
                                             float* __restrict__ outp) {
    __shared__ __align__(16) int Ms[128 * 64];   // 32 KB mask tile (raw int32, swizzled)
    __shared__ __align__(16) u16 Hs[128 * 64];   // 16 KB h tile [d][n] (swizzled)

    const int tid  = threadIdx.x;
    const int lane = tid & 63, wave = tid >> 6;
    const int quad = lane >> 4, l16 = lane & 15;
    const int b0 = (blockIdx.x & 1) * 128;
    const int d0 = (blockIdx.x >> 1) * 128;
    const int wm = wave & 1, wd = wave >> 1;

    acc4 acc[4][4];
#pragma unroll
    for (int rt = 0; rt < 4; ++rt)
#pragma unroll
        for (int dt = 0; dt < 4; ++dt) acc[rt][dt] = (acc4)0.0f;

    for (int it = 0; it < 25; ++it) {
        const int nb = blockIdx.y * 1600 + it * 64;
#pragma unroll
        for (int i = 0; i < 8; ++i) {
            int g = i * 256 + tid;
            int row = g >> 4, c = g & 15;
            gld16(masks + (size_t)(b0 + row) * NND + nb + ((c ^ (row & 15)) << 2), Ms + g * 4);
        }
#pragma unroll
        for (int i = 0; i < 4; ++i) {
            int g = i * 256 + tid;
            int dr = g >> 3, c = g & 7;
            gld16(h_t + (size_t)(d0 + dr) * NND + nb + ((c ^ (dr & 7)) << 3), Hs + g * 8);
        }
        __syncthreads();
#pragma unroll
        for (int ks = 0; ks < 2; ++ks) {
            s8 af[4];
#pragma unroll
            for (int rt = 0; rt < 4; ++rt) {
                int row = wm * 64 + rt * 16 + l16;
                int gi = ks * 8 + quad * 2;
                const int* base = Ms + row * 64;
                i4 m0 = *(const i4*)(base + ((gi ^ l16) << 2));
                i4 m1 = *(const i4*)(base + (((gi + 1) ^ l16) << 2));
                s8 t;
                t[0] = (short)((-m0.x) & 0x3F80); t[1] = (short)((-m0.y) & 0x3F80);
                t[2] = (short)((-m0.z) & 0x3F80); t[3] = (short)((-m0.w) & 0x3F80);
                t[4] = (short)((-m1.x) & 0x3F80); t[5] = (short)((-m1.y) & 0x3F80);
                t[6] = (short)((-m1.z) & 0x3F80); t[7] = (short)((-m1.w) & 0x3F80);
                af[rt] = t;
            }
#pragma unroll
            for (int dt = 0; dt < 4; ++dt) {
                int d = wd * 64 + dt * 16 + l16;
                int slot = (ks * 4 + quad) ^ (l16 & 7);
                s8 bf_ = *(const s8*)&Hs[d * 64 + slot * 8];
#pragma unroll
                for (int rt = 0; rt < 4; ++rt)
                    acc[rt][dt] = __builtin_amdgcn_mfma_f32_16x16x32_bf16(af[rt], bf_, acc[rt][dt], 0, 0, 0);
            }
        }
        __syncthreads();
    }
#pragma unroll
    for (int rt = 0; rt < 4; ++rt)
#pragma unroll
        for (int dt = 0; dt < 4; ++dt) {
            int d  = d0 + wd * 64 + dt * 16 + l16;
            int bb = b0 + wm * 64 + rt * 16 + quad * 4;
#pragma unroll
            for (int r = 0; r < 4; ++r)
                atomicAdd(outp + (size_t)(bb + r) * 256 + d, acc[rt][dt][r]);
        }
}

extern "C" void kernel_launch(void* const* d_in, const int* in_sizes, int n_in,
                              void* d_out, int out_size, void* d_ws, size_t ws_size,
                              hipStream_t stream) {
    const float* nodes = (const float*)d_in[0];
    const int*   masks = (const int*)d_in[1];
    const float* Wt    = (const float*)d_in[2];
    const float* bt    = (const float*)d_in[3];
    const float* Wg    = (const float*)d_in[4];
    const float* bg    = (const float*)d_in[5];
    float* outp = (float*)d_out;

    // ws layout: h_t bf16 [256][200000] = 102,400,000 B; then Wt/Wg bf16 (131072 B). ~102.66 MB total.
    u16* h_t = (u16*)d_ws;
    u16* wtb = (u16*)((char*)d_ws + (size_t)102400000);
    u16* wgb = wtb + 65536;

    hipMemsetAsync(d_out, 0, (size_t)out_size * sizeof(float), stream);
    k_prep<<<dim3(256), dim3(256), 0, stream>>>(Wt, Wg, wtb, wgb);
    k_h<<<dim3(4, 1563), dim3(256), 0, stream>>>(nodes, wtb, wgb, bt, bg, h_t);
    k_res<<<dim3(4, 125), dim3(256), 0, stream>>>(masks, h_t, outp);
}

// Round 2
// 523.933 us; speedup vs baseline: 1.0784x; 1.0784x over previous
//
#include <hip/hip_runtime.h>
#include <stdint.h>

#define NND 200000   // N nodes; D_IN = D_OUT = 256, B = 256

typedef unsigned short u16;
typedef __attribute__((ext_vector_type(4))) float f4;
typedef __attribute__((ext_vector_type(4))) int   i4;
typedef __attribute__((ext_vector_type(2))) unsigned int u2;
typedef __attribute__((ext_vector_type(8))) short s8;   // 8 bf16 - MFMA A/B frag
typedef __attribute__((ext_vector_type(4))) float acc4; // MFMA C/D frag

__device__ __forceinline__ short f2bf(float f) {
    union { float f; uint32_t u; } v; v.f = f;
    uint32_t r = v.u + 0x7FFFu + ((v.u >> 16) & 1u);   // RNE
    return (short)(r >> 16);
}
__device__ __forceinline__ uint32_t pack2bf(float a, float b) {
    uint32_t ua = __float_as_uint(a), ub = __float_as_uint(b);
    ua = ua + 0x7FFFu + ((ua >> 16) & 1u);
    ub = ub + 0x7FFFu + ((ub >> 16) & 1u);
    return (ua >> 16) | (ub & 0xFFFF0000u);
}
__device__ __forceinline__ void gld16(const void* g, void* l) {
    __builtin_amdgcn_global_load_lds(
        (const __attribute__((address_space(1))) void*)g,
        (__attribute__((address_space(3))) void*)l, 16, 0, 0);
}

// ---------------- prep: W fp32 -> bf16 ----------------
__global__ __launch_bounds__(256) void k_prep(const float* __restrict__ Wt,
                                              const float* __restrict__ Wg,
                                              u16* __restrict__ wtb,
                                              u16* __restrict__ wgb) {
    int i = blockIdx.x * 256 + threadIdx.x;   // 256 blocks -> 65536 exactly
    wtb[i] = (u16)f2bf(Wt[i]);
    wgb[i] = (u16)f2bf(Wg[i]);
}

// ---------------- pass 1: h_t[d][n] = (nodes@Wt.T+bt)*sigmoid(nodes@Wg.T+bg) ----------------
// Block: 64 nodes x ALL 256 d (nodes fetched exactly once). 4 waves, wave = 64n x 64d x {T,G}.
// grid 3125 (200000/64).
__global__ __launch_bounds__(256, 2) void k_h(const float* __restrict__ nodes,
                                              const u16* __restrict__ wtb,
                                              const u16* __restrict__ wgb,
                                              const float* __restrict__ btp,
                                              const float* __restrict__ bgp,
                                              u16* __restrict__ h_t) {
    __shared__ __align__(16) char smem[74752];
    u16* Abf = (u16*)smem;               // A bf16: 64 rows x 72 shorts (stride 144 B, 8-short pad)
    u16* Ws0 = (u16*)(smem + 9216);      // Wt tile: 256 d x 64 k bf16, XOR granule swizzle
    u16* Ws1 = (u16*)(smem + 41984);     // Wg tile

    const int tid  = threadIdx.x;
    const int lane = tid & 63, wave = tid >> 6;
    const int quad = lane >> 4, l16 = lane & 15;
    const int n0 = blockIdx.x * 64;

    acc4 at_[4][4], ag_[4][4];
#pragma unroll
    for (int rt = 0; rt < 4; ++rt)
#pragma unroll
        for (int dt = 0; dt < 4; ++dt) { at_[rt][dt] = (acc4)0.0f; ag_[rt][dt] = (acc4)0.0f; }

    for (int kt = 0; kt < 4; ++kt) {
        const int k0 = kt * 64;
        // A: 64x64 fp32, 4 f4 per thread (coalesced: 256B/row contiguous)
        f4 av[4];
#pragma unroll
        for (int i = 0; i < 4; ++i) {
            int f = i * 256 + tid;
            int row = f >> 4, kp = f & 15;
            av[i] = *(const f4*)(nodes + (size_t)(n0 + row) * 256 + k0 + kp * 4);
        }
        // W: 2 x 256x64 bf16 via gld16 (from L2 after first pass), swizzled granules
#pragma unroll
        for (int i = 0; i < 8; ++i) {
            int g = i * 256 + tid;
            int dr = g >> 3, c = g & 7;
            size_t off = (size_t)dr * 256 + k0 + ((c ^ (dr & 7)) << 3);
            gld16(wtb + off, Ws0 + g * 8);
            gld16(wgb + off, Ws1 + g * 8);
        }
        // convert A once per element -> bf16 LDS
#pragma unroll
        for (int i = 0; i < 4; ++i) {
            int f = i * 256 + tid;
            int row = f >> 4, kp = f & 15;
            u2 p; p.x = pack2bf(av[i].x, av[i].y); p.y = pack2bf(av[i].z, av[i].w);
            *(u2*)((char*)Abf + row * 144 + kp * 8) = p;
        }
        __syncthreads();
#pragma unroll
        for (int ks = 0; ks < 2; ++ks) {
            s8 af[4];
#pragma unroll
            for (int rt = 0; rt < 4; ++rt)
                af[rt] = *(const s8*)((char*)Abf + (rt * 16 + l16) * 144 + ks * 64 + quad * 16);
#pragma unroll
            for (int dt = 0; dt < 4; ++dt) {
                int dl = wave * 64 + dt * 16 + l16;
                int slot = (ks * 4 + quad) ^ (dl & 7);
                s8 bT = *(const s8*)(Ws0 + dl * 64 + slot * 8);
                s8 bG = *(const s8*)(Ws1 + dl * 64 + slot * 8);
#pragma unroll
                for (int rt = 0; rt < 4; ++rt) {
                    at_[rt][dt] = __builtin_amdgcn_mfma_f32_16x16x32_bf16(af[rt], bT, at_[rt][dt], 0, 0, 0);
                    ag_[rt][dt] = __builtin_amdgcn_mfma_f32_16x16x32_bf16(af[rt], bG, ag_[rt][dt], 0, 0, 0);
                }
            }
        }
        __syncthreads();
    }

    // epilogue: h = (data+bt)*sigmoid(gate+bg), transpose via LDS -> h_t[d][n] coalesced
    u16* Hs = (u16*)smem;  // 256 d x 72 shorts (stride 144 B)
#pragma unroll
    for (int dt = 0; dt < 4; ++dt) {
        int dl = wave * 64 + dt * 16 + l16;
        float btv = btp[dl], bgv = bgp[dl];
#pragma unroll
        for (int rt = 0; rt < 4; ++rt) {
            float h0, h1, h2, h3;
            float g0 = ag_[rt][dt][0] + bgv, g1 = ag_[rt][dt][1] + bgv;
            float g2 = ag_[rt][dt][2] + bgv, g3 = ag_[rt][dt][3] + bgv;
            h0 = (at_[rt][dt][0] + btv) / (1.0f + __expf(-g0));
            h1 = (at_[rt][dt][1] + btv) / (1.0f + __expf(-g1));
            h2 = (at_[rt][dt][2] + btv) / (1.0f + __expf(-g2));
            h3 = (at_[rt][dt][3] + btv) / (1.0f + __expf(-g3));
            u2 p; p.x = pack2bf(h0, h1); p.y = pack2bf(h2, h3);
            *(u2*)((char*)Hs + dl * 144 + (rt * 16 + quad * 4) * 2) = p;
        }
    }
    __syncthreads();
#pragma unroll
    for (int i = 0; i < 8; ++i) {
        int g = i * 256 + tid;
        int d = g >> 3, c = g & 7;
        f4 v = *(const f4*)((char*)Hs + d * 144 + c * 16);
        *(f4*)(h_t + (size_t)d * NND + n0 + c * 8) = v;
    }
}

// ---------------- pass 2: res = mask @ h_t^T, split-K ----------------
// Block: 128 b x ALL 256 d, grid (2 b-halves, 125 K-splits of 1600). 4 waves: 2b x 2d.
__global__ __launch_bounds__(256, 2) void k_res(const int* __restrict__ masks,
                                                const u16* __restrict__ h_t,
                                                float* __restrict__ outp) {
    __shared__ __align__(16) u16 Ms[128 * 64];   // 16 KB mask bf16 (converted once), swizzled
    __shared__ __align__(16) u16 Hs[256 * 64];   // 32 KB h tile [d][n], swizzled

    const int tid  = threadIdx.x;
    const int lane = tid & 63, wave = tid >> 6;
    const int quad = lane >> 4, l16 = lane & 15;
    const int b0 = blockIdx.x * 128;
    const int wb = wave & 1, wd = wave >> 1;

    acc4 acc[4][8];
#pragma unroll
    for (int rt = 0; rt < 4; ++rt)
#pragma unroll
        for (int dt = 0; dt < 8; ++dt) acc[rt][dt] = (acc4)0.0f;

    for (int it = 0; it < 25; ++it) {
        const int nb = blockIdx.y * 1600 + it * 64;
        // h: 256x64 bf16 via gld16
#pragma unroll
        for (int i = 0; i < 8; ++i) {
            int g = i * 256 + tid;
            int dr = g >> 3, c = g & 7;
            gld16(h_t + (size_t)dr * NND + nb + ((c ^ (dr & 7)) << 3), (char*)Hs + g * 16);
        }
        // masks: 128x64 int32 -> bf16 once, ds_write_b128
#pragma unroll
        for (int i = 0; i < 4; ++i) {
            int g = i * 256 + tid;
            int dr = g >> 3, c = g & 7;
            const i4* mp = (const i4*)(masks + (size_t)(b0 + dr) * NND + nb + c * 8);
            i4 m0 = mp[0], m1 = mp[1];
            i4 w;
            w.x = (int)((((uint32_t)(-m0.x)) & 0x3F80u) | ((((uint32_t)(-m0.y)) & 0x3F80u) << 16));
            w.y = (int)((((uint32_t)(-m0.z)) & 0x3F80u) | ((((uint32_t)(-m0.w)) & 0x3F80u) << 16));
            w.z = (int)((((uint32_t)(-m1.x)) & 0x3F80u) | ((((uint32_t)(-m1.y)) & 0x3F80u) << 16));
            w.w = (int)((((uint32_t)(-m1.z)) & 0x3F80u) | ((((uint32_t)(-m1.w)) & 0x3F80u) << 16));
            *(i4*)((char*)Ms + dr * 128 + ((c ^ (dr & 7)) << 4)) = w;
        }
        __syncthreads();
#pragma unroll
        for (int ks = 0; ks < 2; ++ks) {
            s8 af[4];
#pragma unroll
            for (int rt = 0; rt < 4; ++rt) {
                int r = wb * 64 + rt * 16 + l16;
                af[rt] = *(const s8*)((char*)Ms + r * 128 + (((ks * 4 + quad) ^ (r & 7)) << 4));
            }
#pragma unroll
            for (int dt = 0; dt < 8; ++dt) {
                int dl = wd * 128 + dt * 16 + l16;
                s8 bf_ = *(const s8*)((char*)Hs + dl * 128 + (((ks * 4 + quad) ^ (dl & 7)) << 4));
#pragma unroll
                for (int rt = 0; rt < 4; ++rt)
                    acc[rt][dt] = __builtin_amdgcn_mfma_f32_16x16x32_bf16(af[rt], bf_, acc[rt][dt], 0, 0, 0);
            }
        }
        __syncthreads();
    }
#pragma unroll
    for (int rt = 0; rt < 4; ++rt)
#pragma unroll
        for (int dt = 0; dt < 8; ++dt) {
            int b = b0 + wb * 64 + rt * 16 + quad * 4;
            int d = wd * 128 + dt * 16 + l16;
#pragma unroll
            for (int r = 0; r < 4; ++r)
                atomicAdd(outp + (size_t)(b + r) * 256 + d, acc[rt][dt][r]);
        }
}

extern "C" void kernel_launch(void* const* d_in, const int* in_sizes, int n_in,
                              void* d_out, int out_size, void* d_ws, size_t ws_size,
                              hipStream_t stream) {
    const float* nodes = (const float*)d_in[0];
    const int*   masks = (const int*)d_in[1];
    const float* Wt    = (const float*)d_in[2];
    const float* bt    = (const float*)d_in[3];
    const float* Wg    = (const float*)d_in[4];
    const float* bg    = (const float*)d_in[5];
    float* outp = (float*)d_out;

    // ws layout: h_t bf16 [256][200000] = 102,400,000 B; then Wt/Wg bf16 (131072 B each half)
    u16* h_t = (u16*)d_ws;
    u16* wtb = (u16*)((char*)d_ws + (size_t)102400000);
    u16* wgb = wtb + 65536;

    hipMemsetAsync(d_out, 0, (size_t)out_size * sizeof(float), stream);
    k_prep<<<dim3(256), dim3(256), 0, stream>>>(Wt, Wg, wtb, wgb);
    k_h<<<dim3(3125), dim3(256), 0, stream>>>(nodes, wtb, wgb, bt, bg, h_t);
    k_res<<<dim3(2, 125), dim3(256), 0, stream>>>(masks, h_t, outp);
}

// Round 3
// 501.694 us; speedup vs baseline: 1.1262x; 1.0443x over previous
//
#include <hip/hip_runtime.h>
#include <stdint.h>

#define NND 200000   // N nodes; D_IN = D_OUT = 256, B = 256

typedef unsigned short u16;
typedef __attribute__((ext_vector_type(4))) float f4;
typedef __attribute__((ext_vector_type(4))) int   i4;
typedef __attribute__((ext_vector_type(2))) unsigned int u2;
typedef __attribute__((ext_vector_type(8))) short s8;   // 8 bf16 - MFMA A/B frag
typedef __attribute__((ext_vector_type(4))) float acc4; // MFMA C/D frag

__device__ __forceinline__ short f2bf(float f) {
    union { float f; uint32_t u; } v; v.f = f;
    uint32_t r = v.u + 0x7FFFu + ((v.u >> 16) & 1u);   // RNE
    return (short)(r >> 16);
}
__device__ __forceinline__ uint32_t pack2bf(float a, float b) {
    uint32_t ua = __float_as_uint(a), ub = __float_as_uint(b);
    ua = ua + 0x7FFFu + ((ua >> 16) & 1u);
    ub = ub + 0x7FFFu + ((ub >> 16) & 1u);
    return (ua >> 16) | (ub & 0xFFFF0000u);
}
__device__ __forceinline__ float bf2f(uint32_t s) { return __uint_as_float(s << 16); }
__device__ __forceinline__ void gld16(const void* g, void* l) {
    __builtin_amdgcn_global_load_lds(
        (const __attribute__((address_space(1))) void*)g,
        (__attribute__((address_space(3))) void*)l, 16, 0, 0);
}

// ---------------- prep: W fp32 -> bf16 ----------------
__global__ __launch_bounds__(256) void k_prep(const float* __restrict__ Wt,
                                              const float* __restrict__ Wg,
                                              u16* __restrict__ wtb,
                                              u16* __restrict__ wgb) {
    int i = blockIdx.x * 256 + threadIdx.x;   // 256 blocks -> 65536 exactly
    wtb[i] = (u16)f2bf(Wt[i]);
    wgb[i] = (u16)f2bf(Wg[i]);
}

// ---------------- pass 1: h_t[d][n] = (nodes@Wt.T+bt)*sigmoid(nodes@Wg.T+bg) ----------------
// 512 threads = 8 waves. Block: 64 nodes x 256 d x both matrices.
// Wave w: 32 d (w*32..), all 64 n, both T and G. acc = 64 VGPR/lane.
// LDS 74752 -> 2 blocks/CU; VGPR<=128 -> 4 waves/SIMD -> 16 waves/CU.
__global__ __launch_bounds__(512, 4) void k_h(const float* __restrict__ nodes,
                                              const u16* __restrict__ wtb,
                                              const u16* __restrict__ wgb,
                                              const float* __restrict__ btp,
                                              const float* __restrict__ bgp,
                                              u16* __restrict__ h_t) {
    __shared__ __align__(16) char smem[74752];
    u16* Abf = (u16*)smem;               // 64 rows x 144B (64 bf16 + 16B pad), slot-swizzled
    u16* Ws  = (u16*)(smem + 9216);      // 2 x [256 d x 128B], granule-swizzled (gld16 dest)
    u16* Hs  = (u16*)smem;               // epilogue: 256 d x 144B

    const int tid  = threadIdx.x;
    const int lane = tid & 63, wave = tid >> 6;
    const int quad = lane >> 4, l16 = lane & 15;
    const int n0 = blockIdx.x * 64;
    const int arow = tid >> 3, aslot = tid & 7;

    acc4 at_[4][2], ag_[4][2];
#pragma unroll
    for (int rt = 0; rt < 4; ++rt)
#pragma unroll
        for (int dt = 0; dt < 2; ++dt) { at_[rt][dt] = (acc4)0.0f; ag_[rt][dt] = (acc4)0.0f; }

    for (int kt = 0; kt < 4; ++kt) {
        const int k0 = kt * 64;
        // A prefetch to regs (issued before barrier -> latency overlaps barrier wait)
        const float* ap = nodes + (size_t)(n0 + arow) * 256 + k0 + aslot * 8;
        f4 a0 = ((const f4*)ap)[0];
        f4 a1 = ((const f4*)ap)[1];
        if (kt) __syncthreads();   // protect LDS from previous round's readers
        // W stage: 2 x 256x64 bf16 via gld16 (L2/L3-hot), 8 gld16/thread
#pragma unroll
        for (int i = 0; i < 4; ++i) {
            int g = i * 512 + tid;
            int dr = g >> 3, c = g & 7;
            size_t off = (size_t)dr * 256 + k0 + ((c ^ (dr & 7)) << 3);
            gld16(wtb + off, (char*)Ws + g * 16);
            gld16(wgb + off, (char*)Ws + 32768 + g * 16);
        }
        // A convert once -> bf16 LDS (b128, xor slot swizzle)
        {
            i4 aw;
            aw.x = (int)pack2bf(a0.x, a0.y); aw.y = (int)pack2bf(a0.z, a0.w);
            aw.z = (int)pack2bf(a1.x, a1.y); aw.w = (int)pack2bf(a1.z, a1.w);
            *(i4*)((char*)Abf + arow * 144 + ((aslot ^ (arow & 7)) << 4)) = aw;
        }
        __syncthreads();
        // MFMA: K=64 in two ks halves
#pragma unroll
        for (int ks = 0; ks < 2; ++ks) {
            const int q = (ks << 2) | quad;
            s8 af[4];
#pragma unroll
            for (int rt = 0; rt < 4; ++rt)
                af[rt] = *(const s8*)((char*)Abf + (rt * 16 + l16) * 144 + ((q ^ (l16 & 7)) << 4));
#pragma unroll
            for (int dt = 0; dt < 2; ++dt) {
                int dl = wave * 32 + dt * 16 + l16;
                int sl = (q ^ (dl & 7)) << 4;
                s8 bT = *(const s8*)((char*)Ws + dl * 128 + sl);
                s8 bG = *(const s8*)((char*)Ws + 32768 + dl * 128 + sl);
#pragma unroll
                for (int rt = 0; rt < 4; ++rt) {
                    at_[rt][dt] = __builtin_amdgcn_mfma_f32_16x16x32_bf16(af[rt], bT, at_[rt][dt], 0, 0, 0);
                    ag_[rt][dt] = __builtin_amdgcn_mfma_f32_16x16x32_bf16(af[rt], bG, ag_[rt][dt], 0, 0, 0);
                }
            }
        }
    }
    __syncthreads();   // all waves done reading Ws/Abf before Hs overwrite

    // epilogue: h = (data+bt)*sigmoid(gate+bg) -> bf16 -> LDS transpose
#pragma unroll
    for (int dt = 0; dt < 2; ++dt) {
        int dl = wave * 32 + dt * 16 + l16;
        float btv = btp[dl], bgv = bgp[dl];
#pragma unroll
        for (int rt = 0; rt < 4; ++rt) {
            float h0 = (at_[rt][dt][0] + btv) / (1.0f + __expf(-(ag_[rt][dt][0] + bgv)));
            float h1 = (at_[rt][dt][1] + btv) / (1.0f + __expf(-(ag_[rt][dt][1] + bgv)));
            float h2 = (at_[rt][dt][2] + btv) / (1.0f + __expf(-(ag_[rt][dt][2] + bgv)));
            float h3 = (at_[rt][dt][3] + btv) / (1.0f + __expf(-(ag_[rt][dt][3] + bgv)));
            u2 p; p.x = pack2bf(h0, h1); p.y = pack2bf(h2, h3);
            *(u2*)((char*)Hs + dl * 144 + (rt * 16 + quad * 4) * 2) = p;
        }
    }
    __syncthreads();
    // coalesced store h_t[d][n0..n0+64)
#pragma unroll
    for (int i = 0; i < 4; ++i) {
        int g = i * 512 + tid;
        int d = g >> 3, c = g & 7;
        f4 v = *(const f4*)((char*)Hs + d * 144 + c * 16);
        *(f4*)(h_t + (size_t)d * NND + n0 + c * 8) = v;
    }
}

// ---------------- pass 2: res = mask @ h_t^T, split-K ----------------
// 512 threads = 8 waves. Block: 128 b x 256 d; wave (bh,dq) = 64b x 64d (acc 64 VGPR).
// grid (2, 209): 418 blocks, 15 rounds x 64 n (last split 5). Mask regs prefetched across barrier.
__global__ __launch_bounds__(512, 4) void k_res(const int* __restrict__ masks,
                                                const u16* __restrict__ h_t,
                                                float* __restrict__ outp) {
    __shared__ __align__(16) char smem[49152];
    u16* Ms = (u16*)smem;             // 128 b x 128B bf16, slot-swizzled (reg-written)
    u16* Hs = (u16*)(smem + 16384);   // 256 d x 128B bf16, slot-swizzled (gld16 dest)

    const int tid  = threadIdx.x;
    const int lane = tid & 63, wave = tid >> 6;
    const int quad = lane >> 4, l16 = lane & 15;
    const int bh = wave & 1, dq = wave >> 1;
    const int b0 = blockIdx.x * 128;
    const int nbase = blockIdx.y * 960;
    const int R = min(15, (NND - nbase) / 64);

    acc4 acc[4][4];
#pragma unroll
    for (int rt = 0; rt < 4; ++rt)
#pragma unroll
        for (int dt = 0; dt < 4; ++dt) acc[rt][dt] = (acc4)0.0f;

    const int mr0 = tid >> 3, mc0 = tid & 7;          // i=0 granule
    const int mr1 = (512 + tid) >> 3, mc1 = tid & 7;  // i=1 granule
    i4 mp[2][2];
    {   // prefetch masks for it=0
        const i4* p0 = (const i4*)(masks + (size_t)(b0 + mr0) * NND + nbase + mc0 * 8);
        const i4* p1 = (const i4*)(masks + (size_t)(b0 + mr1) * NND + nbase + mc1 * 8);
        mp[0][0] = p0[0]; mp[0][1] = p0[1];
        mp[1][0] = p1[0]; mp[1][1] = p1[1];
    }

    for (int it = 0; it < R; ++it) {
        const int nb = nbase + it * 64;
        // H: 256x64 bf16 via gld16 (L3-hot from pass 1), 4/thread
#pragma unroll
        for (int i = 0; i < 4; ++i) {
            int g = i * 512 + tid;
            int dr = g >> 3, c = g & 7;
            gld16(h_t + (size_t)dr * NND + nb + ((c ^ (dr & 7)) << 3), (char*)Hs + g * 16);
        }
        // convert prefetched mask regs -> bf16 LDS (b128 each)
#pragma unroll
        for (int i = 0; i < 2; ++i) {
            int mr = (i == 0) ? mr0 : mr1, c = (i == 0) ? mc0 : mc1;
            i4 w;
            w.x = (int)((((uint32_t)(-mp[i][0].x)) & 0x3F80u) | ((((uint32_t)(-mp[i][0].y)) & 0x3F80u) << 16));
            w.y = (int)((((uint32_t)(-mp[i][0].z)) & 0x3F80u) | ((((uint32_t)(-mp[i][0].w)) & 0x3F80u) << 16));
            w.z = (int)((((uint32_t)(-mp[i][1].x)) & 0x3F80u) | ((((uint32_t)(-mp[i][1].y)) & 0x3F80u) << 16));
            w.w = (int)((((uint32_t)(-mp[i][1].z)) & 0x3F80u) | ((((uint32_t)(-mp[i][1].w)) & 0x3F80u) << 16));
            *(i4*)((char*)Ms + mr * 128 + ((c ^ (mr & 7)) << 4)) = w;
        }
        __syncthreads();
        // prefetch next round's masks NOW -> in flight during MFMA
        if (it + 1 < R) {
            const int nn = nb + 64;
            const i4* p0 = (const i4*)(masks + (size_t)(b0 + mr0) * NND + nn + mc0 * 8);
            const i4* p1 = (const i4*)(masks + (size_t)(b0 + mr1) * NND + nn + mc1 * 8);
            mp[0][0] = p0[0]; mp[0][1] = p0[1];
            mp[1][0] = p1[0]; mp[1][1] = p1[1];
        }
#pragma unroll
        for (int ks = 0; ks < 2; ++ks) {
            const int q = (ks << 2) | quad;
            s8 af[4];
#pragma unroll
            for (int rt = 0; rt < 4; ++rt) {
                int r = bh * 64 + rt * 16 + l16;
                af[rt] = *(const s8*)((char*)Ms + r * 128 + ((q ^ (l16 & 7)) << 4));
            }
#pragma unroll
            for (int dt = 0; dt < 4; ++dt) {
                int dl = dq * 64 + dt * 16 + l16;
                s8 bf_ = *(const s8*)((char*)Hs + dl * 128 + ((q ^ (dl & 7)) << 4));
#pragma unroll
                for (int rt = 0; rt < 4; ++rt)
                    acc[rt][dt] = __builtin_amdgcn_mfma_f32_16x16x32_bf16(af[rt], bf_, acc[rt][dt], 0, 0, 0);
            }
        }
        __syncthreads();
    }
#pragma unroll
    for (int rt = 0; rt < 4; ++rt)
#pragma unroll
        for (int dt = 0; dt < 4; ++dt) {
            int b = b0 + bh * 64 + rt * 16 + quad * 4;
            int d = dq * 64 + dt * 16 + l16;
#pragma unroll
            for (int r = 0; r < 4; ++r)
                atomicAdd(outp + (size_t)(b + r) * 256 + d, acc[rt][dt][r]);
        }
}

extern "C" void kernel_launch(void* const* d_in, const int* in_sizes, int n_in,
                              void* d_out, int out_size, void* d_ws, size_t ws_size,
                              hipStream_t stream) {
    const float* nodes = (const float*)d_in[0];
    const int*   masks = (const int*)d_in[1];
    const float* Wt    = (const float*)d_in[2];
    const float* bt    = (const float*)d_in[3];
    const float* Wg    = (const float*)d_in[4];
    const float* bg    = (const float*)d_in[5];
    float* outp = (float*)d_out;

    // ws layout: h_t bf16 [256][200000] = 102,400,000 B; then Wt/Wg bf16 (131072 B)
    u16* h_t = (u16*)d_ws;
    u16* wtb = (u16*)((char*)d_ws + (size_t)102400000);
    u16* wgb = wtb + 65536;

    hipMemsetAsync(d_out, 0, (size_t)out_size * sizeof(float), stream);
    k_prep<<<dim3(256), dim3(256), 0, stream>>>(Wt, Wg, wtb, wgb);
    k_h<<<dim3(3125), dim3(512), 0, stream>>>(nodes, wtb, wgb, bt, bg, h_t);
    k_res<<<dim3(2, 209), dim3(512), 0, stream>>>(masks, h_t, outp);
}